// Round 1
// baseline (516.349 us; speedup 1.0000x reference)
//
#include <hip/hip_runtime.h>
#include <hip/hip_bf16.h>
#include <math.h>

#define NN 2048
#define DA 256
#define DK 64
#define DG 64

__device__ __forceinline__ float wave_reduce_max(float v) {
  #pragma unroll
  for (int o = 32; o >= 1; o >>= 1) v = fmaxf(v, __shfl_xor(v, o, 64));
  return v;
}
__device__ __forceinline__ float wave_reduce_sum(float v) {
  #pragma unroll
  for (int o = 32; o >= 1; o >>= 1) v += __shfl_xor(v, o, 64);
  return v;
}

// One block per row m: stage f_a row in LDS, 192 threads each compute one
// output element of {w_k, w_q, w_v}.
__global__ __launch_bounds__(256) void proj_kernel(
    const float* __restrict__ fa,
    const float* __restrict__ WKw, const float* __restrict__ WKb,
    const float* __restrict__ WQw, const float* __restrict__ WQb,
    const float* __restrict__ WVw, const float* __restrict__ WVb,
    float* __restrict__ wk, float* __restrict__ wq, float* __restrict__ wv)
{
  __shared__ float s_fa[DA];
  const int m = blockIdx.x, tid = threadIdx.x;
  s_fa[tid] = fa[(size_t)m * DA + tid];
  __syncthreads();
  if (tid < 192) {
    const int o = tid >> 6, k = tid & 63;
    const float* W = (o == 0 ? WKw : (o == 1 ? WQw : WVw)) + (size_t)k * DA;
    const float* B = (o == 0 ? WKb : (o == 1 ? WQb : WVb));
    float acc = B[k];
    const float4* W4 = (const float4*)W;
    const float4* F4 = (const float4*)s_fa;
    #pragma unroll 8
    for (int c = 0; c < DA / 4; ++c) {
      float4 w4 = W4[c], f4 = F4[c];
      acc = fmaf(w4.x, f4.x, acc); acc = fmaf(w4.y, f4.y, acc);
      acc = fmaf(w4.z, f4.z, acc); acc = fmaf(w4.w, f4.w, acc);
    }
    float* dst = (o == 0 ? wk : (o == 1 ? wq : wv));
    dst[(size_t)m * DK + k] = acc;
  }
}

// One block (256 threads = 4 waves) per output row m.
// Phase 1: logits for the whole row into LDS (8 KB), streaming pe[m] once.
// Phase 2: block softmax (max-reduce, exp, sum-reduce) in LDS.
// Phase 3: out[m,:] = softmax-row @ w_v, wave-per-n-stripe, lane-per-k.
__global__ __launch_bounds__(256) void fused_kernel(
    const float* __restrict__ pe,
    const float* __restrict__ wgw, const float* __restrict__ wgb,
    const float* __restrict__ wk, const float* __restrict__ wq,
    const float* __restrict__ wv,
    float* __restrict__ out)
{
  __shared__ float s_logit[NN];      // 8 KB: logits, then softmax probs
  __shared__ float s_wg[DG];
  __shared__ float s_wk[DK];
  __shared__ float s_rmax[4], s_rsum[4];
  __shared__ float s_acc[4][DK];

  const int m = blockIdx.x, tid = threadIdx.x;
  const int wave = tid >> 6, lane = tid & 63;
  if (tid < DG) s_wg[tid] = wgw[tid];
  else if (tid >= 64 && tid < 64 + DK) s_wk[tid - 64] = wk[(size_t)m * DK + (tid - 64)];
  __syncthreads();
  const float gb = wgb[0];

  // ---- phase 1: logits ----
  float lmax = -INFINITY;
  #pragma unroll
  for (int i = 0; i < NN / 256; ++i) {
    const int n = i * 256 + tid;
    const float4* p4 = (const float4*)(pe + ((size_t)m * NN + n) * DG);
    const float4* q4 = (const float4*)(wq + (size_t)n * DK);
    const float4* g4 = (const float4*)s_wg;
    const float4* k4 = (const float4*)s_wk;
    float dg = 0.f, dq = 0.f;
    #pragma unroll
    for (int c = 0; c < DG / 4; ++c) {
      float4 p = p4[c], g = g4[c];
      dg = fmaf(p.x, g.x, dg); dg = fmaf(p.y, g.y, dg);
      dg = fmaf(p.z, g.z, dg); dg = fmaf(p.w, g.w, dg);
      float4 q = q4[c], k = k4[c];
      dq = fmaf(q.x, k.x, dq); dq = fmaf(q.y, k.y, dq);
      dq = fmaf(q.z, k.z, dq); dq = fmaf(q.w, k.w, dq);
    }
    // relu then clip(1e-6) then log  ==  log(max(x, 1e-6))
    const float sg = fmaxf(dg + gb, 1e-6f);
    const float logit = __logf(sg) + dq * 0.125f;
    s_logit[n] = logit;
    lmax = fmaxf(lmax, logit);
  }
  lmax = wave_reduce_max(lmax);
  if (lane == 0) s_rmax[wave] = lmax;
  __syncthreads();
  const float rmax = fmaxf(fmaxf(s_rmax[0], s_rmax[1]), fmaxf(s_rmax[2], s_rmax[3]));

  // ---- phase 2: exp + sum ----
  float lsum = 0.f;
  #pragma unroll
  for (int i = 0; i < NN / 256; ++i) {
    const int n = i * 256 + tid;
    const float p = __expf(s_logit[n] - rmax);
    s_logit[n] = p;
    lsum += p;
  }
  lsum = wave_reduce_sum(lsum);
  if (lane == 0) s_rsum[wave] = lsum;
  __syncthreads();
  const float inv = 1.0f / (s_rsum[0] + s_rsum[1] + s_rsum[2] + s_rsum[3]);

  // ---- phase 3: out[m,:] = p-row @ w_v ----
  float acc = 0.f;
  const int n0 = wave * (NN / 4);
  const float* wvp = wv + (size_t)n0 * DK + lane;
  #pragma unroll 8
  for (int n = 0; n < NN / 4; ++n) {
    acc = fmaf(s_logit[n0 + n], wvp[(size_t)n * DK], acc);
  }
  s_acc[wave][lane] = acc;
  __syncthreads();
  if (tid < DK) {
    const float r = (s_acc[0][tid] + s_acc[1][tid] + s_acc[2][tid] + s_acc[3][tid]) * inv;
    out[(size_t)m * DK + tid] = r;
  }
}

extern "C" void kernel_launch(void* const* d_in, const int* in_sizes, int n_in,
                              void* d_out, int out_size, void* d_ws, size_t ws_size,
                              hipStream_t stream) {
  const float* fa  = (const float*)d_in[0];
  const float* pe  = (const float*)d_in[1];
  const float* wgw = (const float*)d_in[2];
  const float* wgb = (const float*)d_in[3];
  const float* wkw = (const float*)d_in[4];
  const float* wkb = (const float*)d_in[5];
  const float* wqw = (const float*)d_in[6];
  const float* wqb = (const float*)d_in[7];
  const float* wvw = (const float*)d_in[8];
  const float* wvb = (const float*)d_in[9];
  float* out = (float*)d_out;

  float* wk = (float*)d_ws;          // [NN, DK]
  float* wq = wk + (size_t)NN * DK;  // [NN, DK]
  float* wv = wq + (size_t)NN * DK;  // [NN, DK]

  proj_kernel<<<NN, 256, 0, stream>>>(fa, wkw, wkb, wqw, wqb, wvw, wvb, wk, wq, wv);
  fused_kernel<<<NN, 256, 0, stream>>>(pe, wgw, wgb, wk, wq, wv, out);
}

// Round 2
// 274.556 us; speedup vs baseline: 1.8807x; 1.8807x over previous
//
#include <hip/hip_runtime.h>
#include <hip/hip_bf16.h>
#include <math.h>

#define NN 2048
#define DA 256
#define DK 64
#define DG 64

__device__ __forceinline__ float wave_reduce_max(float v) {
  #pragma unroll
  for (int o = 32; o >= 1; o >>= 1) v = fmaxf(v, __shfl_xor(v, o, 64));
  return v;
}
__device__ __forceinline__ float wave_reduce_sum(float v) {
  #pragma unroll
  for (int o = 32; o >= 1; o >>= 1) v += __shfl_xor(v, o, 64);
  return v;
}

// One block per row m: stage f_a row in LDS, 192 threads each compute one
// output element of {w_k, w_q, w_v}.
__global__ __launch_bounds__(256) void proj_kernel(
    const float* __restrict__ fa,
    const float* __restrict__ WKw, const float* __restrict__ WKb,
    const float* __restrict__ WQw, const float* __restrict__ WQb,
    const float* __restrict__ WVw, const float* __restrict__ WVb,
    float* __restrict__ wk, float* __restrict__ wq, float* __restrict__ wv)
{
  __shared__ float s_fa[DA];
  const int m = blockIdx.x, tid = threadIdx.x;
  s_fa[tid] = fa[(size_t)m * DA + tid];
  __syncthreads();
  if (tid < 192) {
    const int o = tid >> 6, k = tid & 63;
    const float* W = (o == 0 ? WKw : (o == 1 ? WQw : WVw)) + (size_t)k * DA;
    const float* B = (o == 0 ? WKb : (o == 1 ? WQb : WVb));
    float acc = B[k];
    const float4* W4 = (const float4*)W;
    const float4* F4 = (const float4*)s_fa;
    #pragma unroll 8
    for (int c = 0; c < DA / 4; ++c) {
      float4 w4 = W4[c], f4 = F4[c];
      acc = fmaf(w4.x, f4.x, acc); acc = fmaf(w4.y, f4.y, acc);
      acc = fmaf(w4.z, f4.z, acc); acc = fmaf(w4.w, f4.w, acc);
    }
    float* dst = (o == 0 ? wk : (o == 1 ? wq : wv));
    dst[(size_t)m * DK + k] = acc;
  }
}

// One block (256 threads = 4 waves) per output row m.
// Phase 1: coalesced pe stream — 16 lanes cooperate per n. Per wave-instr the
//          64 lanes read one contiguous 1KB block (lane l -> byte l*16).
//          Cross-lane 16-wide allreduce via 4x shfl_xor for both dots.
// Phase 2: block softmax in LDS.
// Phase 3: out[m,:] = p-row @ w_v (coalesced 256B L2 reads, LDS broadcast).
__global__ __launch_bounds__(256) void fused_kernel(
    const float* __restrict__ pe,
    const float* __restrict__ wgw, const float* __restrict__ wgb,
    const float* __restrict__ wk, const float* __restrict__ wq,
    const float* __restrict__ wv,
    float* __restrict__ out)
{
  __shared__ float s_logit[NN];      // 8 KB: logits, then softmax probs
  __shared__ float s_rmax[4], s_rsum[4];
  __shared__ float s_acc[4][DK];

  const int m = blockIdx.x, tid = threadIdx.x;
  const int wave = tid >> 6, lane = tid & 63;
  const int sub = lane >> 4;         // which of the 4 n's this iter
  const int c4  = lane & 15;         // float4 chunk within the 64-float row

  // loop-invariant per-lane slices of wg and wk[m]
  const float4 wg4 = ((const float4*)wgw)[c4];
  const float4 wk4 = ((const float4*)(wk + (size_t)m * DK))[c4];
  const float gb = wgb[0];

  // ---- phase 1: logits, coalesced ----
  float lmax = -INFINITY;
  const int n0 = wave * (NN / 4);
  #pragma unroll 4
  for (int it = 0; it < (NN / 4) / 4; ++it) {     // 128 iters, 4 n's each
    const int nb = n0 + it * 4;
    // contiguous 1KB: lane l reads float4 #l of the 4-row block
    const float4 p = ((const float4*)(pe + ((size_t)m * NN + nb) * DG))[lane];
    const float4 q = ((const float4*)(wq + (size_t)nb * DK))[lane];
    float dg = p.x * wg4.x, dq = q.x * wk4.x;
    dg = fmaf(p.y, wg4.y, dg); dq = fmaf(q.y, wk4.y, dq);
    dg = fmaf(p.z, wg4.z, dg); dq = fmaf(q.z, wk4.z, dq);
    dg = fmaf(p.w, wg4.w, dg); dq = fmaf(q.w, wk4.w, dq);
    // 16-lane allreduce (both quantities)
    #pragma unroll
    for (int o = 1; o <= 8; o <<= 1) {
      dg += __shfl_xor(dg, o, 64);
      dq += __shfl_xor(dq, o, 64);
    }
    if (c4 == 0) {
      // relu -> clip(1e-6) -> log  ==  log(max(x, 1e-6))
      const float logit = __logf(fmaxf(dg + gb, 1e-6f)) + dq * 0.125f;
      s_logit[nb + sub] = logit;
      lmax = fmaxf(lmax, logit);
    }
  }
  lmax = wave_reduce_max(lmax);
  if (lane == 0) s_rmax[wave] = lmax;
  __syncthreads();
  const float rmax = fmaxf(fmaxf(s_rmax[0], s_rmax[1]), fmaxf(s_rmax[2], s_rmax[3]));

  // ---- phase 2: exp + sum ----
  float lsum = 0.f;
  #pragma unroll
  for (int i = 0; i < NN / 256; ++i) {
    const int n = i * 256 + tid;
    const float p = __expf(s_logit[n] - rmax);
    s_logit[n] = p;
    lsum += p;
  }
  lsum = wave_reduce_sum(lsum);
  if (lane == 0) s_rsum[wave] = lsum;
  __syncthreads();
  const float inv = 1.0f / (s_rsum[0] + s_rsum[1] + s_rsum[2] + s_rsum[3]);

  // ---- phase 3: out[m,:] = p-row @ w_v ----
  float acc = 0.f;
  const int pn0 = wave * (NN / 4);
  const float* wvp = wv + (size_t)pn0 * DK + lane;
  #pragma unroll 8
  for (int n = 0; n < NN / 4; ++n) {
    acc = fmaf(s_logit[pn0 + n], wvp[(size_t)n * DK], acc);
  }
  s_acc[wave][lane] = acc;
  __syncthreads();
  if (tid < DK) {
    const float r = (s_acc[0][tid] + s_acc[1][tid] + s_acc[2][tid] + s_acc[3][tid]) * inv;
    out[(size_t)m * DK + tid] = r;
  }
}

extern "C" void kernel_launch(void* const* d_in, const int* in_sizes, int n_in,
                              void* d_out, int out_size, void* d_ws, size_t ws_size,
                              hipStream_t stream) {
  const float* fa  = (const float*)d_in[0];
  const float* pe  = (const float*)d_in[1];
  const float* wgw = (const float*)d_in[2];
  const float* wgb = (const float*)d_in[3];
  const float* wkw = (const float*)d_in[4];
  const float* wkb = (const float*)d_in[5];
  const float* wqw = (const float*)d_in[6];
  const float* wqb = (const float*)d_in[7];
  const float* wvw = (const float*)d_in[8];
  const float* wvb = (const float*)d_in[9];
  float* out = (float*)d_out;

  float* wk = (float*)d_ws;          // [NN, DK]
  float* wq = wk + (size_t)NN * DK;  // [NN, DK]
  float* wv = wq + (size_t)NN * DK;  // [NN, DK]

  proj_kernel<<<NN, 256, 0, stream>>>(fa, wkw, wkb, wqw, wqb, wvw, wvb, wk, wq, wv);
  fused_kernel<<<NN, 256, 0, stream>>>(pe, wgw, wgb, wk, wq, wv, out);
}

// Round 3
// 267.936 us; speedup vs baseline: 1.9271x; 1.0247x over previous
//
#include <hip/hip_runtime.h>
#include <hip/hip_bf16.h>
#include <math.h>

#define NN 2048
#define DA 256
#define DK 64
#define DG 64

typedef float f32x4 __attribute__((ext_vector_type(4)));

__device__ __forceinline__ float wave_reduce_max(float v) {
  #pragma unroll
  for (int o = 32; o >= 1; o >>= 1) v = fmaxf(v, __shfl_xor(v, o, 64));
  return v;
}
__device__ __forceinline__ float wave_reduce_sum(float v) {
  #pragma unroll
  for (int o = 32; o >= 1; o >>= 1) v += __shfl_xor(v, o, 64);
  return v;
}

// Sum across each 16-lane row, pure VALU (DPP), no LDS pipe.
// quad_perm xor1 (0xB1), quad_perm xor2 (0x4E), row_ror:4 (0x124), row_ror:8 (0x128)
__device__ __forceinline__ float dpp_reduce16(float x) {
  int t;
  t = __builtin_amdgcn_update_dpp(0, __float_as_int(x), 0xB1, 0xF, 0xF, true);
  x += __int_as_float(t);
  t = __builtin_amdgcn_update_dpp(0, __float_as_int(x), 0x4E, 0xF, 0xF, true);
  x += __int_as_float(t);
  t = __builtin_amdgcn_update_dpp(0, __float_as_int(x), 0x124, 0xF, 0xF, true);
  x += __int_as_float(t);
  t = __builtin_amdgcn_update_dpp(0, __float_as_int(x), 0x128, 0xF, 0xF, true);
  x += __int_as_float(t);
  return x;
}

// One block per row m: stage f_a row in LDS, 192 threads each compute one
// output element of {w_k, w_q, w_v}.
__global__ __launch_bounds__(256) void proj_kernel(
    const float* __restrict__ fa,
    const float* __restrict__ WKw, const float* __restrict__ WKb,
    const float* __restrict__ WQw, const float* __restrict__ WQb,
    const float* __restrict__ WVw, const float* __restrict__ WVb,
    float* __restrict__ wk, float* __restrict__ wq, float* __restrict__ wv)
{
  __shared__ float s_fa[DA];
  const int m = blockIdx.x, tid = threadIdx.x;
  s_fa[tid] = fa[(size_t)m * DA + tid];
  __syncthreads();
  if (tid < 192) {
    const int o = tid >> 6, k = tid & 63;
    const float* W = (o == 0 ? WKw : (o == 1 ? WQw : WVw)) + (size_t)k * DA;
    const float* B = (o == 0 ? WKb : (o == 1 ? WQb : WVb));
    float acc = B[k];
    const float4* W4 = (const float4*)W;
    const float4* F4 = (const float4*)s_fa;
    #pragma unroll 8
    for (int c = 0; c < DA / 4; ++c) {
      float4 w4 = W4[c], f4 = F4[c];
      acc = fmaf(w4.x, f4.x, acc); acc = fmaf(w4.y, f4.y, acc);
      acc = fmaf(w4.z, f4.z, acc); acc = fmaf(w4.w, f4.w, acc);
    }
    float* dst = (o == 0 ? wk : (o == 1 ? wq : wv));
    dst[(size_t)m * DK + k] = acc;
  }
}

// One block (256 threads = 4 waves) per output row m.
// Phase 1: coalesced nontemporal pe stream, 16 lanes per n, DPP allreduce.
// Phase 2: block softmax in LDS.
// Phase 3: float4 wv loads (lane = sub x c4), LDS-tile final combine.
__global__ __launch_bounds__(256) void fused_kernel(
    const float* __restrict__ pe,
    const float* __restrict__ wgw, const float* __restrict__ wgb,
    const float* __restrict__ wk, const float* __restrict__ wq,
    const float* __restrict__ wv,
    float* __restrict__ out)
{
  __shared__ float s_logit[NN];          // 8 KB: logits, then probs
  __shared__ float s_rmax[4], s_rsum[4];
  __shared__ float s_pacc[4][4][DK];     // 4 KB partial accumulators

  const int m = blockIdx.x, tid = threadIdx.x;
  const int wave = tid >> 6, lane = tid & 63;
  const int sub = lane >> 4;             // n within the 4-row block
  const int c4  = lane & 15;             // float4 chunk within 64 floats

  // loop-invariant per-lane slices
  const f32x4 wg4 = ((const f32x4*)wgw)[c4];
  const f32x4 wk4 = ((const f32x4*)(wk + (size_t)m * DK))[c4];
  const float gb = wgb[0];

  // ---- phase 1: logits (coalesced 1KB/instr, DPP reduce) ----
  float lmax = -INFINITY;
  const int n0 = wave * (NN / 4);
  #pragma unroll 4
  for (int it = 0; it < (NN / 4) / 4; ++it) {   // 128 iters, 4 n's each
    const int nb = n0 + it * 4;
    const f32x4 p = __builtin_nontemporal_load(
        (const f32x4*)(pe + ((size_t)m * NN + nb) * DG) + lane);
    const f32x4 q = ((const f32x4*)(wq + (size_t)nb * DK))[lane];
    float dg = p.x * wg4.x, dq = q.x * wk4.x;
    dg = fmaf(p.y, wg4.y, dg); dq = fmaf(q.y, wk4.y, dq);
    dg = fmaf(p.z, wg4.z, dg); dq = fmaf(q.z, wk4.z, dq);
    dg = fmaf(p.w, wg4.w, dg); dq = fmaf(q.w, wk4.w, dq);
    dg = dpp_reduce16(dg);
    dq = dpp_reduce16(dq);
    if (c4 == 0) {
      // relu -> clip(1e-6) -> log  ==  log(max(x, 1e-6))
      const float logit = __logf(fmaxf(dg + gb, 1e-6f)) + dq * 0.125f;
      s_logit[nb + sub] = logit;
      lmax = fmaxf(lmax, logit);
    }
  }
  lmax = wave_reduce_max(lmax);
  if (lane == 0) s_rmax[wave] = lmax;
  __syncthreads();
  const float rmax = fmaxf(fmaxf(s_rmax[0], s_rmax[1]), fmaxf(s_rmax[2], s_rmax[3]));

  // ---- phase 2: exp + sum ----
  float lsum = 0.f;
  #pragma unroll
  for (int i = 0; i < NN / 256; ++i) {
    const int n = i * 256 + tid;
    const float p = __expf(s_logit[n] - rmax);
    s_logit[n] = p;
    lsum += p;
  }
  lsum = wave_reduce_sum(lsum);
  if (lane == 0) s_rsum[wave] = lsum;
  __syncthreads();
  const float inv = 1.0f / (s_rsum[0] + s_rsum[1] + s_rsum[2] + s_rsum[3]);

  // ---- phase 3: out[m,:] = p-row @ w_v, float4 loads ----
  f32x4 acc = {0.f, 0.f, 0.f, 0.f};
  #pragma unroll 4
  for (int it = 0; it < (NN / 4) / 4; ++it) {
    const int nb = n0 + it * 4;
    const float pb = s_logit[nb + sub];
    const f32x4 v = ((const f32x4*)(wv + (size_t)(nb + sub) * DK))[c4];
    acc.x = fmaf(pb, v.x, acc.x);
    acc.y = fmaf(pb, v.y, acc.y);
    acc.z = fmaf(pb, v.z, acc.z);
    acc.w = fmaf(pb, v.w, acc.w);
  }
  ((f32x4*)&s_pacc[wave][sub][0])[c4] = acc;
  __syncthreads();
  if (tid < DK) {
    float r = 0.f;
    #pragma unroll
    for (int w = 0; w < 4; ++w)
      #pragma unroll
      for (int s = 0; s < 4; ++s)
        r += s_pacc[w][s][tid];
    out[(size_t)m * DK + tid] = r * inv;
  }
}

extern "C" void kernel_launch(void* const* d_in, const int* in_sizes, int n_in,
                              void* d_out, int out_size, void* d_ws, size_t ws_size,
                              hipStream_t stream) {
  const float* fa  = (const float*)d_in[0];
  const float* pe  = (const float*)d_in[1];
  const float* wgw = (const float*)d_in[2];
  const float* wgb = (const float*)d_in[3];
  const float* wkw = (const float*)d_in[4];
  const float* wkb = (const float*)d_in[5];
  const float* wqw = (const float*)d_in[6];
  const float* wqb = (const float*)d_in[7];
  const float* wvw = (const float*)d_in[8];
  const float* wvb = (const float*)d_in[9];
  float* out = (float*)d_out;

  float* wk = (float*)d_ws;          // [NN, DK]
  float* wq = wk + (size_t)NN * DK;  // [NN, DK]
  float* wv = wq + (size_t)NN * DK;  // [NN, DK]

  proj_kernel<<<NN, 256, 0, stream>>>(fa, wkw, wkb, wqw, wqb, wvw, wvb, wk, wq, wv);
  fused_kernel<<<NN, 256, 0, stream>>>(pe, wgw, wgb, wk, wq, wv, out);
}